// Round 1
// baseline (9671.246 us; speedup 1.0000x reference)
//
#include <hip/hip_runtime.h>
#include <math.h>

// MetaNETS Langevin sampler, MI355X.
// Design: one 64-lane wave per batch element (lane = context point), full 20-step
// loop inside one kernel (batches independent -> no global sync). Weights are
// wave-uniform -> scalar (SGPR) loads; per-point activations (h1, tau) stored in
// LDS as packed bf16 pairs (own-column access, conflict-free, 1 ds_read per 32 FMA).
// All accumulation fp32. Backward needs Wd2^T / Wd1_z^T -> prep kernel into d_ws.

#define B_TOT 2048
#define NPT   64
#define ZD    64
#define RD    128
#define HD    128

__device__ __forceinline__ void wave_sync() {
  // intra-wave LDS produce->consume fence: stop compiler reordering + drain lgkm.
  __builtin_amdgcn_wave_barrier();
  __builtin_amdgcn_s_waitcnt(0xC07F);   // lgkmcnt(0), vmcnt/expcnt untouched
  __builtin_amdgcn_wave_barrier();
}

__device__ __forceinline__ float sigf(float x) {
  return __builtin_amdgcn_rcpf(1.0f + __expf(-x));
}

__device__ __forceinline__ unsigned int packbf(float a, float b) {
  unsigned int ua = __float_as_uint(a);
  unsigned int ub = __float_as_uint(b);
  ua += 0x7FFFu + ((ua >> 16) & 1u);   // RNE bf16 rounding
  ub += 0x7FFFu + ((ub >> 16) & 1u);
  return (ua >> 16) | (ub & 0xFFFF0000u);
}

__global__ void prep_kernel(const float* __restrict__ Wd1, const float* __restrict__ Wd2,
                            float* __restrict__ Wd2T, float* __restrict__ Wd1zT) {
  const int i = blockIdx.x * 256 + threadIdx.x;
  if (i < 128 * 128) {
    const int k = i >> 7, h = i & 127;
    Wd2T[h * 128 + k] = Wd2[k * 128 + h];
  }
  if (i < 64 * 128) {
    const int j = i >> 7, k = i & 127;
    Wd1zT[k * 64 + j] = Wd1[j * 128 + k];
  }
}

__global__ __launch_bounds__(64, 1)
void metanets_kernel(
    const float* __restrict__ x_ctx, const float* __restrict__ y_ctx,
    const float* __restrict__ mask,  const float* __restrict__ z0,
    const float* __restrict__ noises,
    const float* __restrict__ We1, const float* __restrict__ be1,
    const float* __restrict__ We2, const float* __restrict__ be2,
    const float* __restrict__ We3, const float* __restrict__ be3,
    const float* __restrict__ Wd1, const float* __restrict__ bd1,
    const float* __restrict__ Wd2, const float* __restrict__ bd2,
    const float* __restrict__ Wd3, const float* __restrict__ bd3,
    const float* __restrict__ Wf1, const float* __restrict__ bf1,
    const float* __restrict__ Wf2, const float* __restrict__ bf2,
    const float* __restrict__ Wf3, const float* __restrict__ bf3,
    const float* __restrict__ Wd2T, const float* __restrict__ Wd1zT,
    float* __restrict__ out, int steps, float dt, float dco)
{
  // All LDS declared as float; packed bf16 pairs stored via bit-cast (no type-punned
  // pointers so alias analysis stays sane).
  __shared__ float h1pf[64 * 64];   // layer-1 acts, packed bf16 pairs [k/2][point]; reused
  __shared__ float taupf[64 * 64];  // tau (and encoder h2) packed pairs [h/2][point]
  __shared__ float zsh[64];
  __shared__ float zw1[128];        // Wd1_z^T z + bd1  (shared by all points)
  __shared__ float rsh[128];        // encoder output r

  float* tile = h1pf;               // 16 x 73 reduction tile (words 0..1167)
  float* dsum = h1pf + 1200;        // colsum(delta1), 128 (words 1200..1327)
  float* f1sh = h1pf + 1344;        // drift hidden 1 (words 1344..1471)
  float* f2sh = h1pf + 1472;        // drift hidden 2 (words 1472..1599)

  const int lane = threadIdx.x & 63;
  const int b = blockIdx.x;

  const float x0v = x_ctx[(b * NPT + lane) * 2 + 0];
  const float x1v = x_ctx[(b * NPT + lane) * 2 + 1];
  const float yv  = y_ctx[b * NPT + lane];
  const float mk  = mask[b * NPT + lane];

  float msum = mk;
  #pragma unroll
  for (int d = 1; d < 64; d <<= 1) msum += __shfl_xor(msum, d, 64);
  const float inv_msum = 1.0f / fmaxf(msum, 1e-6f);

  zsh[lane] = z0[b * ZD + lane];
  wave_sync();

  // ---------------- encoder: r = meanpool(MLP([x,y])) ----------------
  for (int hb = 0; hb < 8; ++hb) {
    const int h0 = hb * 16;
    float acc[16];
    #pragma unroll
    for (int i = 0; i < 16; ++i) {
      const int h = h0 + i;
      const float s = be1[h] + x0v * We1[0 * HD + h] + x1v * We1[1 * HD + h]
                             + yv  * We1[2 * HD + h];
      acc[i] = s * sigf(s);
    }
    #pragma unroll
    for (int i = 0; i < 16; i += 2)
      h1pf[(h0 + i) / 2 * 64 + lane] = __uint_as_float(packbf(acc[i], acc[i + 1]));
  }
  for (int hb = 0; hb < 8; ++hb) {           // layer 2 -> taupf
    const int h0 = hb * 16;
    float acc[16];
    #pragma unroll
    for (int i = 0; i < 16; ++i) acc[i] = be2[h0 + i];
    for (int k2 = 0; k2 < 64; ++k2) {
      const unsigned int w = __float_as_uint(h1pf[k2 * 64 + lane]);
      const float a0 = __uint_as_float(w << 16);
      const float a1 = __uint_as_float(w & 0xFFFF0000u);
      #pragma unroll
      for (int i = 0; i < 16; ++i) {
        acc[i] = fmaf(a0, We2[(2 * k2) * HD + h0 + i], acc[i]);
        acc[i] = fmaf(a1, We2[(2 * k2 + 1) * HD + h0 + i], acc[i]);
      }
    }
    #pragma unroll
    for (int i = 0; i < 16; i += 2) {
      const float v0 = acc[i] * sigf(acc[i]);
      const float v1 = acc[i + 1] * sigf(acc[i + 1]);
      taupf[(h0 + i) / 2 * 64 + lane] = __uint_as_float(packbf(v0, v1));
    }
  }
  for (int hb = 0; hb < 8; ++hb) {           // layer 3 (linear) -> masked mean -> rsh
    const int h0 = hb * 16;
    float acc[16];
    #pragma unroll
    for (int i = 0; i < 16; ++i) acc[i] = be3[h0 + i];
    for (int k2 = 0; k2 < 64; ++k2) {
      const unsigned int w = __float_as_uint(taupf[k2 * 64 + lane]);
      const float a0 = __uint_as_float(w << 16);
      const float a1 = __uint_as_float(w & 0xFFFF0000u);
      #pragma unroll
      for (int i = 0; i < 16; ++i) {
        acc[i] = fmaf(a0, We3[(2 * k2) * RD + h0 + i], acc[i]);
        acc[i] = fmaf(a1, We3[(2 * k2 + 1) * RD + h0 + i], acc[i]);
      }
    }
    wave_sync();
    #pragma unroll
    for (int i = 0; i < 16; ++i) tile[i * 73 + lane] = acc[i] * mk;
    wave_sync();
    const int row = lane & 15, q = lane >> 4;
    float sv = 0.0f;
    #pragma unroll
    for (int j = 0; j < 16; ++j) sv += tile[row * 73 + q * 16 + j];
    sv += __shfl_xor(sv, 16, 64);
    sv += __shfl_xor(sv, 32, 64);
    if (lane < 16) rsh[h0 + lane] = sv * inv_msum;
    wave_sync();
  }

  // ---------------- Langevin step loop ----------------
  for (int st = 0; st < steps; ++st) {
    const float t = (float)st * dt;

    // zW1[k] = sum_j z[j] Wd1[j,k] + bd1[k]   (shared across the 64 points)
    #pragma unroll
    for (int kk = 0; kk < 2; ++kk) {
      const int k = lane + kk * 64;
      float a = bd1[k];
      for (int j = 0; j < 64; ++j) a = fmaf(zsh[j], Wd1[j * HD + k], a);
      zw1[k] = a;
    }
    wave_sync();

    // decoder layer 1 (per point): s1 = zW1 + x*Wd1[64..65]; h1 -> packed bf16
    for (int k2 = 0; k2 < 64; ++k2) {
      const int ka = 2 * k2, kb2 = 2 * k2 + 1;
      const float sA = zw1[ka]  + x0v * Wd1[64 * HD + ka]  + x1v * Wd1[65 * HD + ka];
      const float sB = zw1[kb2] + x0v * Wd1[64 * HD + kb2] + x1v * Wd1[65 * HD + kb2];
      h1pf[k2 * 64 + lane] = __uint_as_float(packbf(sA * sigf(sA), sB * sigf(sB)));
    }

    // decoder layer 2+3 forward; emit tau = Wd3 * silu'(s2) during epilogue
    float dacc = bd3[0];
    for (int hb = 0; hb < 8; ++hb) {
      const int h0 = hb * 16;
      float acc[16];
      #pragma unroll
      for (int i = 0; i < 16; ++i) acc[i] = bd2[h0 + i];
      for (int k2 = 0; k2 < 64; ++k2) {
        const unsigned int w = __float_as_uint(h1pf[k2 * 64 + lane]);
        const float a0 = __uint_as_float(w << 16);
        const float a1 = __uint_as_float(w & 0xFFFF0000u);
        #pragma unroll
        for (int i = 0; i < 16; ++i) {
          acc[i] = fmaf(a0, Wd2[(2 * k2) * HD + h0 + i], acc[i]);
          acc[i] = fmaf(a1, Wd2[(2 * k2 + 1) * HD + h0 + i], acc[i]);
        }
      }
      float tv[16];
      #pragma unroll
      for (int i = 0; i < 16; ++i) {
        const float s2 = acc[i];
        const float sg = sigf(s2);
        const float w3 = Wd3[h0 + i];
        dacc = fmaf(s2 * sg, w3, dacc);
        tv[i] = w3 * (sg * fmaf(s2, 1.0f - sg, 1.0f));   // Wd3 * silu'(s2)
      }
      #pragma unroll
      for (int i = 0; i < 16; i += 2)
        taupf[(h0 + i) / 2 * 64 + lane] = __uint_as_float(packbf(tv[i], tv[i + 1]));
    }

    const float ebw = t * mk * (dacc - yv);   // t and mask folded into e

    // backward: u = Wd2 @ tau; delta1 = ebw * silu'(s1) * u; dsum = colsum over points
    for (int kb = 0; kb < 8; ++kb) {
      const int k0 = kb * 16;
      float u[16];
      #pragma unroll
      for (int i = 0; i < 16; ++i) u[i] = 0.0f;
      for (int h2 = 0; h2 < 64; ++h2) {
        const unsigned int w = __float_as_uint(taupf[h2 * 64 + lane]);
        const float t0 = __uint_as_float(w << 16);
        const float t1 = __uint_as_float(w & 0xFFFF0000u);
        #pragma unroll
        for (int i = 0; i < 16; ++i) {
          u[i] = fmaf(t0, Wd2T[(2 * h2) * HD + k0 + i], u[i]);
          u[i] = fmaf(t1, Wd2T[(2 * h2 + 1) * HD + k0 + i], u[i]);
        }
      }
      float d1[16];
      #pragma unroll
      for (int i = 0; i < 16; ++i) {
        const int k = k0 + i;
        const float s1 = zw1[k] + x0v * Wd1[64 * HD + k] + x1v * Wd1[65 * HD + k];
        const float sg = sigf(s1);
        const float sp1 = sg * fmaf(s1, 1.0f - sg, 1.0f);
        d1[i] = ebw * sp1 * u[i];
      }
      wave_sync();
      #pragma unroll
      for (int i = 0; i < 16; ++i) tile[i * 73 + lane] = d1[i];
      wave_sync();
      const int row = lane & 15, q = lane >> 4;
      float sv = 0.0f;
      #pragma unroll
      for (int j = 0; j < 16; ++j) sv += tile[row * 73 + q * 16 + j];
      sv += __shfl_xor(sv, 16, 64);
      sv += __shfl_xor(sv, 32, 64);
      if (lane < 16) dsum[k0 + lane] = sv;
      wave_sync();
    }

    // drift MLP: [z, r, t] -> 128 -> 128 -> 64
    #pragma unroll
    for (int kk = 0; kk < 2; ++kk) {
      const int h = lane + kk * 64;
      float a = fmaf(t, Wf1[192 * HD + h], bf1[h]);
      for (int j = 0; j < 64; ++j)  a = fmaf(zsh[j], Wf1[j * HD + h], a);
      for (int j = 0; j < 128; ++j) a = fmaf(rsh[j], Wf1[(64 + j) * HD + h], a);
      f1sh[h] = a * sigf(a);
    }
    wave_sync();
    #pragma unroll
    for (int kk = 0; kk < 2; ++kk) {
      const int h = lane + kk * 64;
      float a = bf2[h];
      for (int j = 0; j < 128; ++j) a = fmaf(f1sh[j], Wf2[j * HD + h], a);
      f2sh[h] = a * sigf(a);
    }
    wave_sync();

    // f3, gz = Wd1_z @ dsum, z update (lane = latent dim j)
    float bj = bf3[lane];
    float gz = 0.0f;
    for (int h = 0; h < 128; ++h) {
      bj = fmaf(f2sh[h], Wf3[h * ZD + lane], bj);
      gz = fmaf(dsum[h], Wd1zT[h * ZD + lane], gz);
    }
    const float zold = zsh[lane];
    float g = zold + gz;                       // t already folded into ebw
    g = fminf(fmaxf(g, -100.0f), 100.0f);
    const float zn = zold + (bj - g) * dt
                   + dco * noises[st * (B_TOT * ZD) + b * ZD + lane];
    wave_sync();
    zsh[lane] = zn;
    wave_sync();
  }

  out[b * ZD + lane] = zsh[lane];
}

extern "C" void kernel_launch(void* const* d_in, const int* in_sizes, int n_in,
                              void* d_out, int out_size, void* d_ws, size_t ws_size,
                              hipStream_t stream) {
  const float* x_ctx  = (const float*)d_in[0];
  const float* y_ctx  = (const float*)d_in[1];
  const float* mask   = (const float*)d_in[2];
  const float* z0     = (const float*)d_in[3];
  const float* noises = (const float*)d_in[4];
  const float* We1 = (const float*)d_in[5];  const float* be1 = (const float*)d_in[6];
  const float* We2 = (const float*)d_in[7];  const float* be2 = (const float*)d_in[8];
  const float* We3 = (const float*)d_in[9];  const float* be3 = (const float*)d_in[10];
  const float* Wd1 = (const float*)d_in[11]; const float* bd1 = (const float*)d_in[12];
  const float* Wd2 = (const float*)d_in[13]; const float* bd2 = (const float*)d_in[14];
  const float* Wd3 = (const float*)d_in[15]; const float* bd3 = (const float*)d_in[16];
  const float* Wf1 = (const float*)d_in[17]; const float* bf1 = (const float*)d_in[18];
  const float* Wf2 = (const float*)d_in[19]; const float* bf2 = (const float*)d_in[20];
  const float* Wf3 = (const float*)d_in[21]; const float* bf3 = (const float*)d_in[22];

  const int steps = in_sizes[4] / (B_TOT * ZD);   // noises = steps*B*ZD
  const float dt  = 1.0f / (float)steps;
  const float dco = (float)sqrt(2.0 / (double)steps);

  float* Wd2T  = (float*)d_ws;            // 128x128
  float* Wd1zT = Wd2T + 128 * 128;        // 128x64  (ws re-poisoned -> prep every call)

  hipLaunchKernelGGL(prep_kernel, dim3(64), dim3(256), 0, stream, Wd1, Wd2, Wd2T, Wd1zT);
  hipLaunchKernelGGL(metanets_kernel, dim3(B_TOT), dim3(64), 0, stream,
      x_ctx, y_ctx, mask, z0, noises,
      We1, be1, We2, be2, We3, be3,
      Wd1, bd1, Wd2, bd2, Wd3, bd3,
      Wf1, bf1, Wf2, bf2, Wf3, bf3,
      Wd2T, Wd1zT, (float*)d_out, steps, dt, dco);
}

// Round 2
// 9613.429 us; speedup vs baseline: 1.0060x; 1.0060x over previous
//
#include <hip/hip_runtime.h>
#include <math.h>

// MetaNETS Langevin sampler, MI355X — round 2.
// 256-thread block = one batch element, 4 waves partition the hidden dim
// (wave w: h in [32w,32w+32) fwd, k in [32w,32w+32) bwd; 32 fp32 accs each).
// h1/tau packed-bf16 LDS shared across the 4 waves -> 4 blocks/CU = 16 waves/CU.
// Per-wave reductions via __shfl_xor butterflies. Weights stay scalar-loaded
// (wave id forced into SGPR via readfirstlane).

#define B_TOT 2048
#define NPT   64
#define ZD    64
#define HD    128

__device__ __forceinline__ float sigf(float x) {
  return __builtin_amdgcn_rcpf(1.0f + __expf(-x));
}

__device__ __forceinline__ unsigned int packbf(float a, float b) {
  unsigned int ua = __float_as_uint(a);
  unsigned int ub = __float_as_uint(b);
  ua += 0x7FFFu + ((ua >> 16) & 1u);   // RNE bf16 rounding
  ub += 0x7FFFu + ((ub >> 16) & 1u);
  return (ua >> 16) | (ub & 0xFFFF0000u);
}

__device__ __forceinline__ float wsum64(float v) {
  #pragma unroll
  for (int d = 1; d < 64; d <<= 1) v += __shfl_xor(v, d, 64);
  return v;
}

__global__ void prep_kernel(const float* __restrict__ Wd1, const float* __restrict__ Wd2,
                            float* __restrict__ Wd2T, float* __restrict__ Wd1zT) {
  const int i = blockIdx.x * 256 + threadIdx.x;
  if (i < 128 * 128) {
    const int k = i >> 7, h = i & 127;
    Wd2T[h * 128 + k] = Wd2[k * 128 + h];
  }
  if (i < 64 * 128) {
    const int j = i >> 7, k = i & 127;
    Wd1zT[k * 64 + j] = Wd1[j * 128 + k];
  }
}

__global__ __launch_bounds__(256, 4)
void metanets_kernel(
    const float* __restrict__ x_ctx, const float* __restrict__ y_ctx,
    const float* __restrict__ mask,  const float* __restrict__ z0,
    const float* __restrict__ noises,
    const float* __restrict__ We1, const float* __restrict__ be1,
    const float* __restrict__ We2, const float* __restrict__ be2,
    const float* __restrict__ We3, const float* __restrict__ be3,
    const float* __restrict__ Wd1, const float* __restrict__ bd1,
    const float* __restrict__ Wd2, const float* __restrict__ bd2,
    const float* __restrict__ Wd3, const float* __restrict__ bd3,
    const float* __restrict__ Wf1, const float* __restrict__ bf1,
    const float* __restrict__ Wf2, const float* __restrict__ bf2,
    const float* __restrict__ Wf3, const float* __restrict__ bf3,
    const float* __restrict__ Wd2T, const float* __restrict__ Wd1zT,
    float* __restrict__ out, int steps, float dt, float dco)
{
  __shared__ float h1pf[64 * 64];   // packed bf16 pairs [k/2][point]
  __shared__ float taupf[64 * 64];  // packed bf16 pairs [h/2][point]
  __shared__ float zsh[64];
  __shared__ float zw1[128];
  __shared__ float rsh[128];
  __shared__ float dsum[128];
  __shared__ float f1sh[128];
  __shared__ float f2sh[128];
  __shared__ float eacc[4 * 64];    // per-wave dacc partials [w][point]
  __shared__ float bgz[128];        // drift-out | gz partials

  const int tid  = threadIdx.x;
  const int lane = tid & 63;                                  // context point
  const int w    = __builtin_amdgcn_readfirstlane(tid >> 6);  // wave id (SGPR)
  const int b    = blockIdx.x;

  const float x0v = x_ctx[(b * NPT + lane) * 2 + 0];
  const float x1v = x_ctx[(b * NPT + lane) * 2 + 1];
  const float yv  = y_ctx[b * NPT + lane];
  const float mk  = mask[b * NPT + lane];
  const float inv_msum = 1.0f / fmaxf(wsum64(mk), 1e-6f);

  if (tid < 64) zsh[tid] = z0[b * ZD + tid];
  __syncthreads();

  const int h0 = 32 * w;   // this wave's h-range (fwd) / k-range (bwd)

  // ---------------- encoder: r = meanpool(MLP([x,y])) ----------------
  {
    for (int k2 = 16 * w; k2 < 16 * w + 16; ++k2) {
      const int ka = 2 * k2, kb = 2 * k2 + 1;
      const float sA = be1[ka] + x0v * We1[0 * HD + ka] + x1v * We1[1 * HD + ka]
                               + yv  * We1[2 * HD + ka];
      const float sB = be1[kb] + x0v * We1[0 * HD + kb] + x1v * We1[1 * HD + kb]
                               + yv  * We1[2 * HD + kb];
      h1pf[k2 * 64 + lane] = __uint_as_float(packbf(sA * sigf(sA), sB * sigf(sB)));
    }
    __syncthreads();

    float acc[32];
    #pragma unroll
    for (int i = 0; i < 32; ++i) acc[i] = be2[h0 + i];
    for (int k2 = 0; k2 < 64; ++k2) {
      const unsigned int wd = __float_as_uint(h1pf[k2 * 64 + lane]);
      const float a0 = __uint_as_float(wd << 16);
      const float a1 = __uint_as_float(wd & 0xFFFF0000u);
      #pragma unroll
      for (int i = 0; i < 32; ++i) {
        acc[i] = fmaf(a0, We2[(2 * k2) * HD + h0 + i], acc[i]);
        acc[i] = fmaf(a1, We2[(2 * k2 + 1) * HD + h0 + i], acc[i]);
      }
    }
    #pragma unroll
    for (int i = 0; i < 32; i += 2) {
      const float v0 = acc[i] * sigf(acc[i]);
      const float v1 = acc[i + 1] * sigf(acc[i + 1]);
      taupf[(h0 + i) / 2 * 64 + lane] = __uint_as_float(packbf(v0, v1));
    }
    __syncthreads();

    #pragma unroll
    for (int i = 0; i < 32; ++i) acc[i] = be3[h0 + i];
    for (int k2 = 0; k2 < 64; ++k2) {
      const unsigned int wd = __float_as_uint(taupf[k2 * 64 + lane]);
      const float a0 = __uint_as_float(wd << 16);
      const float a1 = __uint_as_float(wd & 0xFFFF0000u);
      #pragma unroll
      for (int i = 0; i < 32; ++i) {
        acc[i] = fmaf(a0, We3[(2 * k2) * HD + h0 + i], acc[i]);
        acc[i] = fmaf(a1, We3[(2 * k2 + 1) * HD + h0 + i], acc[i]);
      }
    }
    #pragma unroll
    for (int i = 0; i < 32; ++i) {
      const float v = wsum64(acc[i] * mk);
      if (lane == 0) rsh[h0 + i] = v * inv_msum;
    }
    __syncthreads();
  }

  // ---------------- Langevin step loop ----------------
  for (int st = 0; st < steps; ++st) {
    const float t = (float)st * dt;

    // zW1[k] = bd1[k] + sum_j z[j] Wd1[j,k]   (shared across points)
    if (tid < 128) {
      float a = bd1[tid];
      for (int j = 0; j < 64; ++j) a = fmaf(zsh[j], Wd1[j * HD + tid], a);
      zw1[tid] = a;
    }
    __syncthreads();

    // decoder layer 1: wave w writes packed words [16w,16w+16)
    for (int k2 = 16 * w; k2 < 16 * w + 16; ++k2) {
      const int ka = 2 * k2, kb = 2 * k2 + 1;
      const float sA = zw1[ka] + x0v * Wd1[64 * HD + ka] + x1v * Wd1[65 * HD + ka];
      const float sB = zw1[kb] + x0v * Wd1[64 * HD + kb] + x1v * Wd1[65 * HD + kb];
      h1pf[k2 * 64 + lane] = __uint_as_float(packbf(sA * sigf(sA), sB * sigf(sB)));
    }
    __syncthreads();

    // decoder layer 2+3 forward (wave w: h in [h0,h0+32)); emit tau + dacc partial
    {
      float acc[32];
      #pragma unroll
      for (int i = 0; i < 32; ++i) acc[i] = bd2[h0 + i];
      for (int k2 = 0; k2 < 64; ++k2) {
        const unsigned int wd = __float_as_uint(h1pf[k2 * 64 + lane]);
        const float a0 = __uint_as_float(wd << 16);
        const float a1 = __uint_as_float(wd & 0xFFFF0000u);
        #pragma unroll
        for (int i = 0; i < 32; ++i) {
          acc[i] = fmaf(a0, Wd2[(2 * k2) * HD + h0 + i], acc[i]);
          acc[i] = fmaf(a1, Wd2[(2 * k2 + 1) * HD + h0 + i], acc[i]);
        }
      }
      float dacc_w = 0.0f;
      #pragma unroll
      for (int i = 0; i < 32; i += 2) {
        const float s2a = acc[i], s2b = acc[i + 1];
        const float sga = sigf(s2a), sgb = sigf(s2b);
        const float w3a = Wd3[h0 + i], w3b = Wd3[h0 + i + 1];
        dacc_w = fmaf(s2a * sga, w3a, dacc_w);
        dacc_w = fmaf(s2b * sgb, w3b, dacc_w);
        const float tva = w3a * (sga * fmaf(s2a, 1.0f - sga, 1.0f));
        const float tvb = w3b * (sgb * fmaf(s2b, 1.0f - sgb, 1.0f));
        taupf[(h0 + i) / 2 * 64 + lane] = __uint_as_float(packbf(tva, tvb));
      }
      eacc[w * 64 + lane] = dacc_w;
    }
    __syncthreads();

    const float dacc = bd3[0] + eacc[lane] + eacc[64 + lane]
                              + eacc[128 + lane] + eacc[192 + lane];
    const float ebw = t * mk * (dacc - yv);   // t and mask folded into e

    // backward (wave w: k in [h0,h0+32)): u = Wd2T-slice @ tau; dsum = colsum(delta1)
    {
      float u[32];
      #pragma unroll
      for (int i = 0; i < 32; ++i) u[i] = 0.0f;
      for (int h2 = 0; h2 < 64; ++h2) {
        const unsigned int wd = __float_as_uint(taupf[h2 * 64 + lane]);
        const float t0 = __uint_as_float(wd << 16);
        const float t1 = __uint_as_float(wd & 0xFFFF0000u);
        #pragma unroll
        for (int i = 0; i < 32; ++i) {
          u[i] = fmaf(t0, Wd2T[(2 * h2) * HD + h0 + i], u[i]);
          u[i] = fmaf(t1, Wd2T[(2 * h2 + 1) * HD + h0 + i], u[i]);
        }
      }
      #pragma unroll
      for (int i = 0; i < 32; ++i) {
        const int k = h0 + i;
        const float s1 = zw1[k] + x0v * Wd1[64 * HD + k] + x1v * Wd1[65 * HD + k];
        const float sg = sigf(s1);
        const float d1 = ebw * (sg * fmaf(s1, 1.0f - sg, 1.0f)) * u[i];
        const float v = wsum64(d1);
        if (lane == 0) dsum[k] = v;
      }
    }
    __syncthreads();

    // drift MLP: [z, r, t] -> 128 -> 128 -> 64
    if (tid < 128) {
      float a = fmaf(t, Wf1[192 * HD + tid], bf1[tid]);
      for (int j = 0; j < 64; ++j)  a = fmaf(zsh[j], Wf1[j * HD + tid], a);
      for (int j = 0; j < 128; ++j) a = fmaf(rsh[j], Wf1[(64 + j) * HD + tid], a);
      f1sh[tid] = a * sigf(a);
    }
    __syncthreads();
    if (tid < 128) {
      float a = bf2[tid];
      for (int j = 0; j < 128; ++j) a = fmaf(f1sh[j], Wf2[j * HD + tid], a);
      f2sh[tid] = a * sigf(a);
    }
    __syncthreads();
    if (tid < 128) {
      if (tid < 64) {
        float a = bf3[tid];
        for (int h = 0; h < 128; ++h) a = fmaf(f2sh[h], Wf3[h * ZD + tid], a);
        bgz[tid] = a;                              // drift output b_j
      } else {
        const int j = tid - 64;
        float a = 0.0f;
        for (int h = 0; h < 128; ++h) a = fmaf(dsum[h], Wd1zT[h * ZD + j], a);
        bgz[64 + j] = a;                           // gz_j (t already in ebw)
      }
    }
    __syncthreads();
    if (tid < 64) {
      const float zold = zsh[tid];
      float g = zold + bgz[64 + tid];
      g = fminf(fmaxf(g, -100.0f), 100.0f);
      zsh[tid] = zold + (bgz[tid] - g) * dt
               + dco * noises[(size_t)st * (B_TOT * ZD) + b * ZD + tid];
    }
    __syncthreads();
  }

  if (tid < 64) out[b * ZD + tid] = zsh[tid];
}

extern "C" void kernel_launch(void* const* d_in, const int* in_sizes, int n_in,
                              void* d_out, int out_size, void* d_ws, size_t ws_size,
                              hipStream_t stream) {
  const float* x_ctx  = (const float*)d_in[0];
  const float* y_ctx  = (const float*)d_in[1];
  const float* mask   = (const float*)d_in[2];
  const float* z0     = (const float*)d_in[3];
  const float* noises = (const float*)d_in[4];
  const float* We1 = (const float*)d_in[5];  const float* be1 = (const float*)d_in[6];
  const float* We2 = (const float*)d_in[7];  const float* be2 = (const float*)d_in[8];
  const float* We3 = (const float*)d_in[9];  const float* be3 = (const float*)d_in[10];
  const float* Wd1 = (const float*)d_in[11]; const float* bd1 = (const float*)d_in[12];
  const float* Wd2 = (const float*)d_in[13]; const float* bd2 = (const float*)d_in[14];
  const float* Wd3 = (const float*)d_in[15]; const float* bd3 = (const float*)d_in[16];
  const float* Wf1 = (const float*)d_in[17]; const float* bf1 = (const float*)d_in[18];
  const float* Wf2 = (const float*)d_in[19]; const float* bf2 = (const float*)d_in[20];
  const float* Wf3 = (const float*)d_in[21]; const float* bf3 = (const float*)d_in[22];

  const int steps = in_sizes[4] / (B_TOT * ZD);
  const float dt  = 1.0f / (float)steps;
  const float dco = (float)sqrt(2.0 / (double)steps);

  float* Wd2T  = (float*)d_ws;            // 128x128
  float* Wd1zT = Wd2T + 128 * 128;        // 128x64

  hipLaunchKernelGGL(prep_kernel, dim3(64), dim3(256), 0, stream, Wd1, Wd2, Wd2T, Wd1zT);
  hipLaunchKernelGGL(metanets_kernel, dim3(B_TOT), dim3(256), 0, stream,
      x_ctx, y_ctx, mask, z0, noises,
      We1, be1, We2, be2, We3, be3,
      Wd1, bd1, Wd2, bd2, Wd3, bd3,
      Wf1, bf1, Wf2, bf2, Wf3, bf3,
      Wd2T, Wd1zT, (float*)d_out, steps, dt, dco);
}